// Round 9
// baseline (106.124 us; speedup 1.0000x reference)
//
#include <hip/hip_runtime.h>

#define WIRE_DIM  32
#define NUM_WIRES 64
#define BATCH     8192
#define HID       10
#define HSTRIDE   20   // half-row LDS stride: 16 floats data + 4 pad.
                       // reads: quad-bank (5*l)%8 -> 8 distinct per phase, conflict-free
                       // writes: 4 lanes/quad-bank balanced, conflict-free

// broadcast-read a float from a wave-uniform lane index -> scalar
__device__ __forceinline__ float rl(float x, int slane) {
    return __uint_as_float(__builtin_amdgcn_readlane(__float_as_uint(x), slane));
}

// (256,8): force the 64-VGPR budget -> 8 waves/SIMD. Hand count fits: c[8]=32
// + acc=10 + x,p=8 + temps ~10 = ~60. (R2's hint-spill had ~110 live in 64 —
// the hint is only safe when the live set fits, which it now does.)
__global__ __launch_bounds__(256, 8) void isnet_kernel(
    const float* __restrict__ outputs,
    const int*   __restrict__ tests,
    const float* __restrict__ W1,
    const float* __restrict__ bias1,
    const float* __restrict__ W2,
    const float* __restrict__ bias2,
    float*       __restrict__ out)
{
    // 4 waves x 64 rows x 20 floats = 20 KB/block -> 8 blocks/CU -> 32 waves/CU
    // (R6-8 used 36KB -> 16 waves/CU; 3 neutral rounds point at occupancy)
    __shared__ __align__(16) float stage[4][NUM_WIRES * HSTRIDE];

    const int tid  = threadIdx.x;
    const int lane = tid & 63;
    const int wave = tid >> 6;
    float* buf = stage[wave];

    const int b = blockIdx.x * 4 + wave;          // one batch per wave

    const int sp = __builtin_amdgcn_readfirstlane(tests[2 * b]);      // person
    const int sl = __builtin_amdgcn_readfirstlane(tests[2 * b + 1]);  // location

    // ---- 8 fully-coalesced 1KB loads (unchanged: 100% sector efficiency) ----
    // lane l gets chunk (l&7) of rows 8t+(l>>3), t=0..7
    const float* g = outputs + (size_t)b * (NUM_WIRES * WIRE_DIM) + lane * 4;
    float4 c[8];
    #pragma unroll
    for (int t = 0; t < 8; ++t) c[t] = *(const float4*)(g + t * 256);

    const int r0   = lane >> 3;                   // row offset within group
    const int cpos = (lane & 3) * 4;              // chunk slot within half-row
    const bool loA = (lane & 7) < 4;              // holds chunks 0..3

    float acc[HID];
    #pragma unroll
    for (int h = 0; h < HID; ++h) acc[h] = bias1[h];   // uniform -> s_load

    #pragma unroll
    for (int pass = 0; pass < 2; ++pass) {
        // stage this pass's half-rows: chunks 4*pass..4*pass+3 of all 64 rows,
        // held by lanes with (l&7)<4 (pass 0) / >=4 (pass 1). Exec-masked.
        if (loA == (pass == 0)) {
            #pragma unroll
            for (int t = 0; t < 8; ++t)
                *(float4*)&buf[(t * 8 + r0) * HSTRIDE + cpos] = c[t];
        }
        // wave-private buffer: compiler orders via lgkmcnt, no __syncthreads

        #pragma unroll 1
        for (int jj = 0; jj < 4; ++jj) {
            float4 x = *(const float4*)&buf[lane * HSTRIDE + jj * 4]; // own wire
            float4 p = *(const float4*)&buf[sp   * HSTRIDE + jj * 4]; // person (bcast)
            const int j = pass * 4 + jj;
            const float* wp = W1 + (4 * j) * HID;        // person rows 4j..4j+3
            const float* ww = W1 + (32 + 4 * j) * HID;   // wire rows 32+4j..
            #pragma unroll
            for (int h = 0; h < HID; ++h) {
                acc[h] += p.x * wp[0 * HID + h] + p.y * wp[1 * HID + h]
                        + p.z * wp[2 * HID + h] + p.w * wp[3 * HID + h]
                        + x.x * ww[0 * HID + h] + x.y * ww[1 * HID + h]
                        + x.z * ww[2 * HID + h] + x.w * ww[3 * HID + h];
            }
        }
    }

    // ---- relu -> W2 -> logit per lane(=wire) -> wave softmax -> loss ----
    float v = bias2[0];
    #pragma unroll
    for (int h = 0; h < HID; ++h) v += fmaxf(acc[h], 0.f) * W2[h];

    float m = v;
    #pragma unroll
    for (int off = 32; off > 0; off >>= 1) m = fmaxf(m, __shfl_xor(m, off));
    float s = __expf(v - m);
    #pragma unroll
    for (int off = 32; off > 0; off >>= 1) s += __shfl_xor(s, off);
    float lv = rl(v, sl);                        // logit at `location`
    if (lane == 0) out[b] = m + __logf(s) - lv;  // -log_softmax[loc]
}

extern "C" void kernel_launch(void* const* d_in, const int* in_sizes, int n_in,
                              void* d_out, int out_size, void* d_ws, size_t ws_size,
                              hipStream_t stream) {
    const float* outputs = (const float*)d_in[0];
    const int*   tests   = (const int*)d_in[1];
    const float* W1      = (const float*)d_in[2];
    const float* b1      = (const float*)d_in[3];
    const float* W2      = (const float*)d_in[4];
    const float* b2      = (const float*)d_in[5];
    float* out = (float*)d_out;

    // 2048 blocks x 4 waves x 1 batch; 8 blocks/CU -> full 32-wave occupancy,
    // entire problem resident in one generation
    isnet_kernel<<<BATCH / 4, 256, 0, stream>>>(
        outputs, tests, W1, b1, W2, b2, out);
}